// Round 9
// baseline (400.617 us; speedup 1.0000x reference)
//
#include <hip/hip_runtime.h>
#include <math.h>

#define NODES   50000
#define HEADS   4
#define HID     64
#define FDIM    256   // HEADS*HID
#define IN_CH   16
#define NEG_SLOPE 0.2f

typedef unsigned short ushort_t;
typedef unsigned int uint_t;
typedef __attribute__((ext_vector_type(8))) short bf16x8;
typedef __attribute__((ext_vector_type(4))) float f32x4;
typedef __attribute__((ext_vector_type(2))) float f32x2;

__device__ inline ushort_t f2bf(float f) {           // RNE fp32 -> bf16
    uint_t u = __float_as_uint(f);
    u += 0x7fffu + ((u >> 16) & 1u);
    return (ushort_t)(u >> 16);
}
__device__ inline void unpack2(uint_t u, float& a, float& b) {
    a = __uint_as_float(u << 16);
    b = __uint_as_float(u & 0xffff0000u);
}
__device__ inline uint_t f2h(float f) {              // fp32 -> fp16 bits (RTE)
    _Float16 h = (_Float16)f;
    return (uint_t)*(ushort_t*)&h;
}
__device__ inline float h2f(uint_t u) {              // fp16 bits -> fp32
    ushort_t us = (ushort_t)u;
    _Float16 h = *(_Float16*)&us;
    return (float)h;
}

// ---------------- merged: layer-1 GEMM + alpha1 | W2T transpose | degree hist ----------------

__global__ __launch_bounds__(256) void k_prep(const float* __restrict__ x,
                                              const float* __restrict__ W1,
                                              const float* __restrict__ as1,
                                              const float* __restrict__ ad1,
                                              const float* __restrict__ W2,
                                              const int* __restrict__ ei, int E,
                                              ushort_t* __restrict__ h,
                                              float* __restrict__ asrc,
                                              float* __restrict__ adst,
                                              ushort_t* __restrict__ W2T,
                                              int* __restrict__ deg, int Nn) {
    int bid = blockIdx.x, t = threadIdx.x;
    if (bid >= Nn + 256) {                 // histogram tail
        int e = (bid - Nn - 256) * 256 + t;
        int Etot = E + Nn;
        if (e >= Etot) return;
        int d = (e < E) ? ei[E + e] : (e - E);
        if (d >= 0 && d < Nn) atomicAdd(&deg[d], 1);
        return;
    }
    if (bid >= Nn) {                       // W2T: 256 blocks, 65536 elements
        int idx = (bid - Nn) * 256 + t;
        int n = idx >> 8, k = idx & 255;
        W2T[idx] = f2bf(W2[k * FDIM + n]);
        return;
    }
    const float4* xp = (const float4*)(x + bid * IN_CH);
    float4 x0 = xp[0], x1 = xp[1], x2 = xp[2], x3 = xp[3];
    float s = x0.x * W1[t]            + x0.y * W1[FDIM + t]
            + x0.z * W1[2 * FDIM + t] + x0.w * W1[3 * FDIM + t]
            + x1.x * W1[4 * FDIM + t] + x1.y * W1[5 * FDIM + t]
            + x1.z * W1[6 * FDIM + t] + x1.w * W1[7 * FDIM + t]
            + x2.x * W1[8 * FDIM + t] + x2.y * W1[9 * FDIM + t]
            + x2.z * W1[10 * FDIM + t]+ x2.w * W1[11 * FDIM + t]
            + x3.x * W1[12 * FDIM + t]+ x3.y * W1[13 * FDIM + t]
            + x3.z * W1[14 * FDIM + t]+ x3.w * W1[15 * FDIM + t];
    h[(long)bid * FDIM + t] = f2bf(s);
    float p1 = s * as1[t];   // as1/ad1 are [H][64] flat == [t]
    float p2 = s * ad1[t];
#pragma unroll
    for (int off = 1; off < 64; off <<= 1) {
        p1 += __shfl_xor(p1, off);
        p2 += __shfl_xor(p2, off);
    }
    if ((t & 63) == 0) {
        int hh = t >> 6;
        asrc[bid * 4 + hh] = p1;
        adst[bid * 4 + hh] = p2;
    }
}

// ---------------- parallel exclusive scan ----------------

__global__ __launch_bounds__(256) void k_scanA(const int* __restrict__ deg,
                                               int* __restrict__ bsum, int N) {
    __shared__ int sh[256];
    int t = threadIdx.x;
    int i0 = blockIdx.x * 4096 + t * 16;
    int s = 0;
#pragma unroll
    for (int j = 0; j < 16; ++j) s += (i0 + j < N) ? deg[i0 + j] : 0;
    sh[t] = s;
    __syncthreads();
    for (int off = 128; off; off >>= 1) {
        if (t < off) sh[t] += sh[t + off];
        __syncthreads();
    }
    if (t == 0) bsum[blockIdx.x] = sh[0];
}

__global__ void k_scanB(int* __restrict__ bsum, int* __restrict__ rowst, int nb, int N) {
    int t = threadIdx.x;   // single wave of 64
    int orig = (t < nb) ? bsum[t] : 0;
    int v = orig;
#pragma unroll
    for (int off = 1; off < 64; off <<= 1) {
        int u = __shfl_up(v, off);
        if (t >= off) v += u;
    }
    if (t < nb) bsum[t] = v - orig;       // exclusive
    if (t == 63) rowst[N] = v;            // grand total
}

__global__ __launch_bounds__(256) void k_scanC(const int* __restrict__ deg,
                                               const int* __restrict__ bsum,
                                               int* __restrict__ rowst,
                                               int* __restrict__ cursor, int N) {
    __shared__ int sh[256];
    int t = threadIdx.x, b = blockIdx.x;
    int i0 = b * 4096 + t * 16;
    int v[16], s = 0;
#pragma unroll
    for (int j = 0; j < 16; ++j) { v[j] = (i0 + j < N) ? deg[i0 + j] : 0; s += v[j]; }
    sh[t] = s;
    __syncthreads();
    for (int off = 1; off < 256; off <<= 1) {
        int u = (t >= off) ? sh[t - off] : 0;
        __syncthreads();
        sh[t] += u;
        __syncthreads();
    }
    int excl = sh[t] - s + bsum[b];
#pragma unroll
    for (int j = 0; j < 16; ++j) {
        if (i0 + j < N) { rowst[i0 + j] = excl; cursor[i0 + j] = excl; }
        excl += v[j];
    }
}

__global__ void k_scatter(const int* __restrict__ ei, int E, int N,
                          int* __restrict__ cursor, int2* __restrict__ csr2) {
    int e = blockIdx.x * blockDim.x + threadIdx.x;
    int Etot = E + N;
    if (e >= Etot) return;
    int s, d;
    if (e < E) { s = ei[e]; d = ei[E + e]; } else { s = d = e - E; }
    if (d < 0 || d >= N) return;
    int pos = atomicAdd(&cursor[d], 1);
    csr2[pos] = make_int2(s, d);
}

// ---------------- layer-2 GEMM (MFMA bf16) ----------------

__global__ __launch_bounds__(256) void k_gemm2(const ushort_t* __restrict__ A,
                                               const ushort_t* __restrict__ BT,
                                               ushort_t* __restrict__ C, int M) {
    __shared__ short As[64 * 40];
    __shared__ short Bs[64 * 40];
    int tid = threadIdx.x;
    int row0 = blockIdx.y * 64, col0 = blockIdx.x * 64;
    int wid = tid >> 6, lane = tid & 63;
    int wm = wid >> 1, wn = wid & 1;
    int quad = lane >> 4, lm = lane & 15;
    int lr = tid >> 2, lk = (tid & 3) * 8;
    f32x4 acc[2][2] = {};
    for (int k0 = 0; k0 < FDIM; k0 += 32) {
        uint4 av = {0u, 0u, 0u, 0u};
        int ar = row0 + lr;
        if (ar < M) av = *(const uint4*)(A + (long)ar * FDIM + k0 + lk);
        *(uint4*)(&As[lr * 40 + lk]) = av;
        uint4 bv = *(const uint4*)(BT + (long)(col0 + lr) * FDIM + k0 + lk);
        *(uint4*)(&Bs[lr * 40 + lk]) = bv;
        __syncthreads();
        bf16x8 a0 = *(const bf16x8*)(&As[(wm * 32 + lm) * 40 + quad * 8]);
        bf16x8 a1 = *(const bf16x8*)(&As[(wm * 32 + 16 + lm) * 40 + quad * 8]);
        bf16x8 b0 = *(const bf16x8*)(&Bs[(wn * 32 + lm) * 40 + quad * 8]);
        bf16x8 b1 = *(const bf16x8*)(&Bs[(wn * 32 + 16 + lm) * 40 + quad * 8]);
        acc[0][0] = __builtin_amdgcn_mfma_f32_16x16x32_bf16(a0, b0, acc[0][0], 0, 0, 0);
        acc[0][1] = __builtin_amdgcn_mfma_f32_16x16x32_bf16(a0, b1, acc[0][1], 0, 0, 0);
        acc[1][0] = __builtin_amdgcn_mfma_f32_16x16x32_bf16(a1, b0, acc[1][0], 0, 0, 0);
        acc[1][1] = __builtin_amdgcn_mfma_f32_16x16x32_bf16(a1, b1, acc[1][1], 0, 0, 0);
        __syncthreads();
    }
#pragma unroll
    for (int mi = 0; mi < 2; ++mi)
#pragma unroll
        for (int ni = 0; ni < 2; ++ni)
#pragma unroll
            for (int r = 0; r < 4; ++r) {
                int row = row0 + wm * 32 + mi * 16 + quad * 4 + r;
                int col = col0 + wn * 32 + ni * 16 + lm;
                if (row < M) C[(long)row * FDIM + col] = f2bf(acc[mi][ni][r]);
            }
}

// ---------------- per-(node,head) attention dots (layer 2) ----------------

__global__ void k_alpha(const ushort_t* __restrict__ h, const float* __restrict__ a_s,
                        const float* __restrict__ a_d, float* __restrict__ asrc,
                        float* __restrict__ adst, int Nn) {
    int idx = blockIdx.x * blockDim.x + threadIdx.x;
    if (idx >= Nn * HEADS) return;
    int n = idx >> 2, hh = idx & 3;
    const uint4* hp = (const uint4*)(h + (long)n * FDIM + hh * HID);
    const float* asp = a_s + hh * HID;
    const float* adp = a_d + hh * HID;
    float s1 = 0.f, s2 = 0.f;
#pragma unroll
    for (int q = 0; q < 8; ++q) {
        uint4 u = hp[q];
        float f[8];
        unpack2(u.x, f[0], f[1]); unpack2(u.y, f[2], f[3]);
        unpack2(u.z, f[4], f[5]); unpack2(u.w, f[6], f[7]);
#pragma unroll
        for (int j = 0; j < 8; ++j) { s1 += f[j] * asp[q * 8 + j]; s2 += f[j] * adp[q * 8 + j]; }
    }
    asrc[idx] = s1;
    adst[idx] = s2;
}

// ---------------- edge-parallel pw precompute: u32 = (src<<16) | fp16(pw) ----------------

__global__ void k_pw(const int2* __restrict__ csr2, const float* __restrict__ asrc,
                     const float* __restrict__ adst, uint_t* __restrict__ pwb, int Etot) {
    int e = blockIdx.x * blockDim.x + threadIdx.x;
    if (e >= Etot) return;
    int2 sd = csr2[e];
    float4 av = *(const float4*)(asrc + sd.x * 4);
    float4 dv = *(const float4*)(adst + sd.y * 4);
    float t[4] = {av.x + dv.x, av.y + dv.y, av.z + dv.z, av.w + dv.w};
    uint_t sh = (uint_t)sd.x << 16;
#pragma unroll
    for (int h = 0; h < 4; ++h) {
        float tt = (t[h] > 0.f) ? t[h] : NEG_SLOPE * t[h];
        pwb[h * Etot + e] = sh | f2h(__expf(tt));
    }
}

// ---------------- segment-softmax aggregate (R6 design: pwb, 4x in flight) ----------------
// block 256 = 4 waves (head = wave); half-wave = one dst node;
// 4 edge-subgroups x 8 channel-octs; 4 edges/lane in flight per iteration.
// mode 1: +b1, ELU, write bf16 hact.  mode 0: head-mean + b2 + ELU + GEMV -> out.

__device__ inline void fma8(f32x2& a0, f32x2& a1, f32x2& a2, f32x2& a3,
                            uint4 hv, float pw) {
    f32x2 p = {pw, pw};
    f32x2 u;
    u.x = __uint_as_float(hv.x << 16); u.y = __uint_as_float(hv.x & 0xffff0000u);
    a0 += p * u;
    u.x = __uint_as_float(hv.y << 16); u.y = __uint_as_float(hv.y & 0xffff0000u);
    a1 += p * u;
    u.x = __uint_as_float(hv.z << 16); u.y = __uint_as_float(hv.z & 0xffff0000u);
    a2 += p * u;
    u.x = __uint_as_float(hv.w << 16); u.y = __uint_as_float(hv.w & 0xffff0000u);
    a3 += p * u;
}

__global__ __launch_bounds__(256) void k_agg(const ushort_t* __restrict__ h,
                                             const uint_t* __restrict__ pwb,
                                             const int* __restrict__ row_start,
                                             const float* __restrict__ b1,
                                             const float* __restrict__ b2,
                                             const float* __restrict__ Wc,
                                             const float* __restrict__ bc,
                                             ushort_t* __restrict__ hout,
                                             float* __restrict__ fout,
                                             int mode, int Etot, int N) {
    __shared__ float zsh[2 * FDIM];    // 2 nodes x 256 ch (head-major)
    __shared__ float wsh[584];         // Wc(512) | bc(8) | b2(64)
    int tid  = threadIdx.x;
    int hh   = tid >> 6;
    int lane = tid & 63;
    int half = lane >> 5;
    int l32  = lane & 31;
    int g    = l32 >> 3;       // edge subgroup 0..3
    int cg   = l32 & 7;        // channel oct 0..7
    int d    = blockIdx.x * 2 + half;
    bool valid = d < N;

    if (!mode) {
        for (int i = tid; i < 584; i += 256)
            wsh[i] = (i < 512) ? Wc[i] : ((i < 520) ? bc[i - 512] : b2[i - 520]);
    }

    int s0 = 0, s1 = 0;
    if (valid) { s0 = row_start[d]; s1 = row_start[d + 1]; }
    int cnt  = s1 - s0;
    int maxc = max(cnt, __shfl_xor(cnt, 32));
    const uint_t* pwp = pwb + (long)hh * Etot;
    const char* hbase = (const char*)h + (hh * HID + cg * 8) * 2;

    f32x2 a0 = {0.f, 0.f}, a1 = {0.f, 0.f}, a2 = {0.f, 0.f}, a3 = {0.f, 0.f};
    float den = 0.f;

    for (int off = 0; off < maxc; off += 16) {
        int i0 = s0 + off + g;
        uint_t u0 = (i0      < s1) ? pwp[i0]      : 0u;
        uint_t u1 = (i0 + 4  < s1) ? pwp[i0 + 4]  : 0u;
        uint_t u2 = (i0 + 8  < s1) ? pwp[i0 + 8]  : 0u;
        uint_t u3 = (i0 + 12 < s1) ? pwp[i0 + 12] : 0u;
        uint4 hv0 = *(const uint4*)(hbase + ((size_t)(u0 >> 16) << 9));
        uint4 hv1 = *(const uint4*)(hbase + ((size_t)(u1 >> 16) << 9));
        uint4 hv2 = *(const uint4*)(hbase + ((size_t)(u2 >> 16) << 9));
        uint4 hv3 = *(const uint4*)(hbase + ((size_t)(u3 >> 16) << 9));
        float pw0 = h2f(u0 & 0xffffu), pw1 = h2f(u1 & 0xffffu);
        float pw2 = h2f(u2 & 0xffffu), pw3 = h2f(u3 & 0xffffu);
        den += (pw0 + pw1) + (pw2 + pw3);
        fma8(a0, a1, a2, a3, hv0, pw0);
        fma8(a0, a1, a2, a3, hv1, pw1);
        fma8(a0, a1, a2, a3, hv2, pw2);
        fma8(a0, a1, a2, a3, hv3, pw3);
    }
    // reduce across the 4 edge-subgroups within each 32-lane half
#pragma unroll
    for (int off = 8; off <= 16; off <<= 1) {
        a0.x += __shfl_xor(a0.x, off); a0.y += __shfl_xor(a0.y, off);
        a1.x += __shfl_xor(a1.x, off); a1.y += __shfl_xor(a1.y, off);
        a2.x += __shfl_xor(a2.x, off); a2.y += __shfl_xor(a2.y, off);
        a3.x += __shfl_xor(a3.x, off); a3.y += __shfl_xor(a3.y, off);
        den  += __shfl_xor(den, off);
    }

    if (mode) {
        if (g == 0 && valid) {
            float inv = 1.f / den;
            float v[8] = {a0.x, a0.y, a1.x, a1.y, a2.x, a2.y, a3.x, a3.y};
            const float* bp = b1 + hh * HID + cg * 8;
#pragma unroll
            for (int j = 0; j < 8; ++j) {
                float t = v[j] * inv + bp[j];
                v[j] = (t > 0.f) ? t : __expf(t) - 1.f;
            }
            uint4 u;
            u.x = (uint_t)f2bf(v[0]) | ((uint_t)f2bf(v[1]) << 16);
            u.y = (uint_t)f2bf(v[2]) | ((uint_t)f2bf(v[3]) << 16);
            u.z = (uint_t)f2bf(v[4]) | ((uint_t)f2bf(v[5]) << 16);
            u.w = (uint_t)f2bf(v[6]) | ((uint_t)f2bf(v[7]) << 16);
            *(uint4*)(hout + (long)d * FDIM + hh * HID + cg * 8) = u;
        }
    } else {
        if (g == 0 && valid) {
            float inv = 1.f / den;
            float v[8] = {a0.x, a0.y, a1.x, a1.y, a2.x, a2.y, a3.x, a3.y};
            int zb = half * FDIM + hh * HID + cg * 8;
#pragma unroll
            for (int j = 0; j < 8; ++j) zsh[zb + j] = v[j] * inv;
        }
        __syncthreads();
        if (tid < 128) {                 // head-mean + b2 + ELU
            int node = tid >> 6, c = tid & 63;
            int dd = blockIdx.x * 2 + node;
            if (dd < N) {
                const float* zp = zsh + node * FDIM;
                float zv = 0.25f * (zp[c] + zp[64 + c] + zp[128 + c] + zp[192 + c])
                         + wsh[520 + c];
                zv = (zv > 0.f) ? zv : __expf(zv) - 1.f;
                zsh[node * FDIM + c] = zv;
            }
        }
        __syncthreads();
        if (tid < 16) {                  // GEMV [64x8] + bc
            int node = tid >> 3, o = tid & 7;
            int dd = blockIdx.x * 2 + node;
            if (dd < N) {
                float acc = wsh[512 + o];
                const float* zp = zsh + node * FDIM;
#pragma unroll 8
                for (int c = 0; c < 64; ++c) acc += zp[c] * wsh[c * 8 + o];
                fout[(long)dd * 8 + o] = acc;
            }
        }
    }
}

// ---------------- launch ----------------

extern "C" void kernel_launch(void* const* d_in, const int* in_sizes, int n_in,
                              void* d_out, int out_size, void* d_ws, size_t ws_size,
                              hipStream_t stream) {
    const float* x   = (const float*)d_in[0];
    const int*   ei  = (const int*)d_in[1];
    const float* W1  = (const float*)d_in[2];
    const float* as1 = (const float*)d_in[3];
    const float* ad1 = (const float*)d_in[4];
    const float* b1  = (const float*)d_in[5];
    const float* W2  = (const float*)d_in[6];
    const float* as2 = (const float*)d_in[7];
    const float* ad2 = (const float*)d_in[8];
    const float* b2  = (const float*)d_in[9];
    const float* Wc  = (const float*)d_in[10];
    const float* bc  = (const float*)d_in[11];
    float* out = (float*)d_out;

    const int N = NODES;
    const int E = in_sizes[1] / 2;
    const int Etot = E + N;

    char* ws = (char*)d_ws;
    size_t off = 0;
    auto alloc = [&](size_t bytes) {
        void* p = ws + off;
        off = (off + bytes + 255) & ~(size_t)255;
        return p;
    };
    ushort_t* hbf    = (ushort_t*)alloc((size_t)N * FDIM * 2);   // h (bf16), both layers
    ushort_t* hact   = (ushort_t*)alloc((size_t)N * FDIM * 2);   // act1 (bf16)
    float*    asrc   = (float*)alloc((size_t)N * HEADS * 4);
    float*    adst   = (float*)alloc((size_t)N * HEADS * 4);
    ushort_t* W2T    = (ushort_t*)alloc((size_t)FDIM * FDIM * 2);
    int*      deg    = (int*)alloc((size_t)N * 4);
    int*      rowst  = (int*)alloc((size_t)(N + 1) * 4);
    int*      cursor = (int*)alloc((size_t)N * 4);
    int*      bsum   = (int*)alloc(64 * 4);
    int2*     csr2   = (int2*)alloc((size_t)Etot * 8);
    uint_t*   pwb    = (uint_t*)alloc((size_t)Etot * HEADS * 4);

    const int tpb = 256;
    int egrid = (Etot + tpb - 1) / tpb;
    int nb = (N + 4095) / 4096;

    hipMemsetAsync(deg, 0, (size_t)N * 4, stream);

    // Merged: layer-1 gemm+alpha | W2T | histogram
    k_prep<<<N + 256 + egrid, tpb, 0, stream>>>(x, W1, as1, ad1, W2, ei, E,
                                                hbf, asrc, adst, W2T, deg, N);
    k_scanA<<<nb, 256, 0, stream>>>(deg, bsum, N);
    k_scanB<<<1, 64, 0, stream>>>(bsum, rowst, nb, N);
    k_scanC<<<nb, 256, 0, stream>>>(deg, bsum, rowst, cursor, N);
    k_scatter<<<egrid, tpb, 0, stream>>>(ei, E, N, cursor, csr2);

    // Layer 1 aggregate (+b1, ELU)
    k_pw<<<egrid, tpb, 0, stream>>>(csr2, asrc, adst, pwb, Etot);
    k_agg<<<(N + 1) / 2, 256, 0, stream>>>(hbf, pwb, rowst, b1, nullptr, nullptr, nullptr,
                                           hact, nullptr, 1, Etot, N);

    // Layer 2
    dim3 g2(FDIM / 64, (N + 63) / 64);
    k_gemm2<<<g2, 256, 0, stream>>>(hact, W2T, hbf, N);
    k_alpha<<<(N * HEADS + tpb - 1) / tpb, tpb, 0, stream>>>(hbf, as2, ad2, asrc, adst, N);
    k_pw<<<egrid, tpb, 0, stream>>>(csr2, asrc, adst, pwb, Etot);
    k_agg<<<(N + 1) / 2, 256, 0, stream>>>(hbf, pwb, rowst, nullptr, b2, Wc, bc,
                                           nullptr, out, 0, Etot, N);
}

// Round 10
// 380.099 us; speedup vs baseline: 1.0540x; 1.0540x over previous
//
#include <hip/hip_runtime.h>
#include <math.h>

#define NODES   50000
#define HEADS   4
#define HID     64
#define FDIM    256   // HEADS*HID
#define IN_CH   16
#define NEG_SLOPE 0.2f

typedef unsigned short ushort_t;
typedef unsigned int uint_t;
typedef __attribute__((ext_vector_type(8))) short bf16x8;
typedef __attribute__((ext_vector_type(4))) float f32x4;
typedef __attribute__((ext_vector_type(2))) float f32x2;

__device__ inline ushort_t f2bf(float f) {           // RNE fp32 -> bf16
    uint_t u = __float_as_uint(f);
    u += 0x7fffu + ((u >> 16) & 1u);
    return (ushort_t)(u >> 16);
}
__device__ inline uint_t f2h(float f) {              // fp32 -> fp16 bits (RTE)
    _Float16 h = (_Float16)f;
    return (uint_t)*(ushort_t*)&h;
}
__device__ inline float h2f(uint_t u) {              // fp16 bits -> fp32
    ushort_t us = (ushort_t)u;
    _Float16 h = *(_Float16*)&us;
    return (float)h;
}

// ---------------- merged: layer-1 GEMM + alpha1 (8 nodes/block) | W2T | hist ----------------
// node blocks: thread = channel, wave = head; 8 nodes per block, W1 column in VGPRs,
// x via scalar loads, interleaved shuffle-reduce chains.

__global__ __launch_bounds__(256) void k_prep(const float* __restrict__ x,
                                              const float* __restrict__ W1,
                                              const float* __restrict__ as1,
                                              const float* __restrict__ ad1,
                                              const float* __restrict__ W2,
                                              const int* __restrict__ ei, int E,
                                              ushort_t* __restrict__ h,
                                              float* __restrict__ asrc,
                                              float* __restrict__ adst,
                                              ushort_t* __restrict__ W2T,
                                              int* __restrict__ deg, int Nn, int NB) {
    int bid = blockIdx.x, t = threadIdx.x;
    if (bid >= NB + 256) {                 // histogram tail
        int e = (bid - NB - 256) * 256 + t;
        int Etot = E + Nn;
        if (e >= Etot) return;
        int d = (e < E) ? ei[E + e] : (e - E);
        if (d >= 0 && d < Nn) atomicAdd(&deg[d], 1);
        return;
    }
    if (bid >= NB) {                       // W2T: 256 blocks, 65536 elements
        int idx = (bid - NB) * 256 + t;
        int n = idx >> 8, k = idx & 255;
        W2T[idx] = f2bf(W2[k * FDIM + n]);
        return;
    }
    float w1c[16];
#pragma unroll
    for (int k = 0; k < 16; ++k) w1c[k] = W1[k * FDIM + t];
    float av = as1[t], dv = ad1[t];       // as1/ad1 are [H][64] flat == [t]
    int hh = t >> 6;
#pragma unroll
    for (int j = 0; j < 8; ++j) {
        int n = bid * 8 + j;
        if (n >= Nn) break;
        const float4* xp = (const float4*)(x + n * IN_CH);
        float4 x0 = xp[0], x1 = xp[1], x2 = xp[2], x3 = xp[3];
        float s = x0.x * w1c[0]  + x0.y * w1c[1]  + x0.z * w1c[2]  + x0.w * w1c[3]
                + x1.x * w1c[4]  + x1.y * w1c[5]  + x1.z * w1c[6]  + x1.w * w1c[7]
                + x2.x * w1c[8]  + x2.y * w1c[9]  + x2.z * w1c[10] + x2.w * w1c[11]
                + x3.x * w1c[12] + x3.y * w1c[13] + x3.z * w1c[14] + x3.w * w1c[15];
        uint_t pv = (uint_t)f2bf(s);
        uint_t ov = __shfl_down(pv, 1);
        if (!(t & 1)) *(uint_t*)(h + (long)n * FDIM + t) = pv | (ov << 16);
        float p1 = s * av, p2 = s * dv;
#pragma unroll
        for (int off = 1; off < 64; off <<= 1) {
            p1 += __shfl_xor(p1, off);
            p2 += __shfl_xor(p2, off);
        }
        if ((t & 63) == 0) {
            asrc[n * 4 + hh] = p1;
            adst[n * 4 + hh] = p2;
        }
    }
}

// ---------------- parallel exclusive scan ----------------

__global__ __launch_bounds__(256) void k_scanA(const int* __restrict__ deg,
                                               int* __restrict__ bsum, int N) {
    __shared__ int sh[256];
    int t = threadIdx.x;
    int i0 = blockIdx.x * 4096 + t * 16;
    int s = 0;
#pragma unroll
    for (int j = 0; j < 16; ++j) s += (i0 + j < N) ? deg[i0 + j] : 0;
    sh[t] = s;
    __syncthreads();
    for (int off = 128; off; off >>= 1) {
        if (t < off) sh[t] += sh[t + off];
        __syncthreads();
    }
    if (t == 0) bsum[blockIdx.x] = sh[0];
}

__global__ void k_scanB(int* __restrict__ bsum, int* __restrict__ rowst, int nb, int N) {
    int t = threadIdx.x;   // single wave of 64
    int orig = (t < nb) ? bsum[t] : 0;
    int v = orig;
#pragma unroll
    for (int off = 1; off < 64; off <<= 1) {
        int u = __shfl_up(v, off);
        if (t >= off) v += u;
    }
    if (t < nb) bsum[t] = v - orig;       // exclusive
    if (t == 63) rowst[N] = v;            // grand total
}

__global__ __launch_bounds__(256) void k_scanC(const int* __restrict__ deg,
                                               const int* __restrict__ bsum,
                                               int* __restrict__ rowst,
                                               int* __restrict__ cursor, int N) {
    __shared__ int sh[256];
    int t = threadIdx.x, b = blockIdx.x;
    int i0 = b * 4096 + t * 16;
    int v[16], s = 0;
#pragma unroll
    for (int j = 0; j < 16; ++j) { v[j] = (i0 + j < N) ? deg[i0 + j] : 0; s += v[j]; }
    sh[t] = s;
    __syncthreads();
    for (int off = 1; off < 256; off <<= 1) {
        int u = (t >= off) ? sh[t - off] : 0;
        __syncthreads();
        sh[t] += u;
        __syncthreads();
    }
    int excl = sh[t] - s + bsum[b];
#pragma unroll
    for (int j = 0; j < 16; ++j) {
        if (i0 + j < N) { rowst[i0 + j] = excl; cursor[i0 + j] = excl; }
        excl += v[j];
    }
}

__global__ void k_scatter(const int* __restrict__ ei, int E, int N,
                          int* __restrict__ cursor, int2* __restrict__ csr2) {
    int e = blockIdx.x * blockDim.x + threadIdx.x;
    int Etot = E + N;
    if (e >= Etot) return;
    int s, d;
    if (e < E) { s = ei[e]; d = ei[E + e]; } else { s = d = e - E; }
    if (d < 0 || d >= N) return;
    int pos = atomicAdd(&cursor[d], 1);
    csr2[pos] = make_int2(s, d);
}

// ---------------- layer-2 GEMM (MFMA bf16) + fused alpha2 dots ----------------
// col tile (64) == one head, so each block owns complete (row, head) dot products.

__global__ __launch_bounds__(256) void k_gemm2(const ushort_t* __restrict__ A,
                                               const ushort_t* __restrict__ BT,
                                               const float* __restrict__ as2,
                                               const float* __restrict__ ad2,
                                               ushort_t* __restrict__ C,
                                               float* __restrict__ asrc,
                                               float* __restrict__ adst, int M) {
    __shared__ short As[64 * 40];
    __shared__ short Bs[64 * 40];
    __shared__ float2 red[64][2];
    int tid = threadIdx.x;
    int row0 = blockIdx.y * 64, col0 = blockIdx.x * 64;
    int wid = tid >> 6, lane = tid & 63;
    int wm = wid >> 1, wn = wid & 1;
    int quad = lane >> 4, lm = lane & 15;
    int lr = tid >> 2, lk = (tid & 3) * 8;
    f32x4 acc[2][2] = {};
    for (int k0 = 0; k0 < FDIM; k0 += 32) {
        uint4 av = {0u, 0u, 0u, 0u};
        int ar = row0 + lr;
        if (ar < M) av = *(const uint4*)(A + (long)ar * FDIM + k0 + lk);
        *(uint4*)(&As[lr * 40 + lk]) = av;
        uint4 bv = *(const uint4*)(BT + (long)(col0 + lr) * FDIM + k0 + lk);
        *(uint4*)(&Bs[lr * 40 + lk]) = bv;
        __syncthreads();
        bf16x8 a0 = *(const bf16x8*)(&As[(wm * 32 + lm) * 40 + quad * 8]);
        bf16x8 a1 = *(const bf16x8*)(&As[(wm * 32 + 16 + lm) * 40 + quad * 8]);
        bf16x8 b0 = *(const bf16x8*)(&Bs[(wn * 32 + lm) * 40 + quad * 8]);
        bf16x8 b1 = *(const bf16x8*)(&Bs[(wn * 32 + 16 + lm) * 40 + quad * 8]);
        acc[0][0] = __builtin_amdgcn_mfma_f32_16x16x32_bf16(a0, b0, acc[0][0], 0, 0, 0);
        acc[0][1] = __builtin_amdgcn_mfma_f32_16x16x32_bf16(a0, b1, acc[0][1], 0, 0, 0);
        acc[1][0] = __builtin_amdgcn_mfma_f32_16x16x32_bf16(a1, b0, acc[1][0], 0, 0, 0);
        acc[1][1] = __builtin_amdgcn_mfma_f32_16x16x32_bf16(a1, b1, acc[1][1], 0, 0, 0);
        __syncthreads();
    }
    // C store
#pragma unroll
    for (int mi = 0; mi < 2; ++mi)
#pragma unroll
        for (int ni = 0; ni < 2; ++ni)
#pragma unroll
            for (int r = 0; r < 4; ++r) {
                int row = row0 + wm * 32 + mi * 16 + quad * 4 + r;
                int col = col0 + wn * 32 + ni * 16 + lm;
                if (row < M) C[(long)row * FDIM + col] = f2bf(acc[mi][ni][r]);
            }
    // fused alpha2: per-row dots vs as2/ad2 (this block's head = blockIdx.x)
    float asv0 = as2[col0 + wn * 32 + lm], asv1 = as2[col0 + wn * 32 + 16 + lm];
    float adv0 = ad2[col0 + wn * 32 + lm], adv1 = ad2[col0 + wn * 32 + 16 + lm];
#pragma unroll
    for (int mi = 0; mi < 2; ++mi)
#pragma unroll
        for (int r = 0; r < 4; ++r) {
            float ps = acc[mi][0][r] * asv0 + acc[mi][1][r] * asv1;
            float pd = acc[mi][0][r] * adv0 + acc[mi][1][r] * adv1;
#pragma unroll
            for (int off = 1; off < 16; off <<= 1) {
                ps += __shfl_xor(ps, off);
                pd += __shfl_xor(pd, off);
            }
            if (lm == 0) red[wm * 32 + mi * 16 + quad * 4 + r][wn] = make_float2(ps, pd);
        }
    __syncthreads();
    if (tid < 64) {
        int row = row0 + tid;
        if (row < M) {
            float2 e0 = red[tid][0], e1 = red[tid][1];
            asrc[row * 4 + blockIdx.x] = e0.x + e1.x;
            adst[row * 4 + blockIdx.x] = e0.y + e1.y;
        }
    }
}

// ---------------- edge-parallel pw precompute: u32 = (src<<16) | fp16(pw) ----------------

__global__ void k_pw(const int2* __restrict__ csr2, const float* __restrict__ asrc,
                     const float* __restrict__ adst, uint_t* __restrict__ pwb, int Etot) {
    int e = blockIdx.x * blockDim.x + threadIdx.x;
    if (e >= Etot) return;
    int2 sd = csr2[e];
    float4 av = *(const float4*)(asrc + sd.x * 4);
    float4 dv = *(const float4*)(adst + sd.y * 4);
    float t[4] = {av.x + dv.x, av.y + dv.y, av.z + dv.z, av.w + dv.w};
    uint_t sh = (uint_t)sd.x << 16;
#pragma unroll
    for (int h = 0; h < 4; ++h) {
        float tt = (t[h] > 0.f) ? t[h] : NEG_SLOPE * t[h];
        pwb[h * Etot + e] = sh | f2h(__expf(tt));
    }
}

// ---------------- segment-softmax aggregate (pwb, 4x in flight, fused epilogues) ----------------

__device__ inline void fma8(f32x2& a0, f32x2& a1, f32x2& a2, f32x2& a3,
                            uint4 hv, float pw) {
    f32x2 p = {pw, pw};
    f32x2 u;
    u.x = __uint_as_float(hv.x << 16); u.y = __uint_as_float(hv.x & 0xffff0000u);
    a0 += p * u;
    u.x = __uint_as_float(hv.y << 16); u.y = __uint_as_float(hv.y & 0xffff0000u);
    a1 += p * u;
    u.x = __uint_as_float(hv.z << 16); u.y = __uint_as_float(hv.z & 0xffff0000u);
    a2 += p * u;
    u.x = __uint_as_float(hv.w << 16); u.y = __uint_as_float(hv.w & 0xffff0000u);
    a3 += p * u;
}

__global__ __launch_bounds__(256) void k_agg(const ushort_t* __restrict__ h,
                                             const uint_t* __restrict__ pwb,
                                             const int* __restrict__ row_start,
                                             const float* __restrict__ b1,
                                             const float* __restrict__ b2,
                                             const float* __restrict__ Wc,
                                             const float* __restrict__ bc,
                                             ushort_t* __restrict__ hout,
                                             float* __restrict__ fout,
                                             int mode, int Etot, int N) {
    __shared__ float zsh[2 * FDIM];    // 2 nodes x 256 ch (head-major)
    __shared__ float wsh[584];         // Wc(512) | bc(8) | b2(64)
    int tid  = threadIdx.x;
    int hh   = tid >> 6;
    int lane = tid & 63;
    int half = lane >> 5;
    int l32  = lane & 31;
    int g    = l32 >> 3;       // edge subgroup 0..3
    int cg   = l32 & 7;        // channel oct 0..7
    int d    = blockIdx.x * 2 + half;
    bool valid = d < N;

    if (!mode) {
        for (int i = tid; i < 584; i += 256)
            wsh[i] = (i < 512) ? Wc[i] : ((i < 520) ? bc[i - 512] : b2[i - 520]);
    }

    int s0 = 0, s1 = 0;
    if (valid) { s0 = row_start[d]; s1 = row_start[d + 1]; }
    int cnt  = s1 - s0;
    int maxc = max(cnt, __shfl_xor(cnt, 32));
    const uint_t* pwp = pwb + (long)hh * Etot;
    const char* hbase = (const char*)h + (hh * HID + cg * 8) * 2;

    f32x2 a0 = {0.f, 0.f}, a1 = {0.f, 0.f}, a2 = {0.f, 0.f}, a3 = {0.f, 0.f};
    float den = 0.f;

    for (int off = 0; off < maxc; off += 16) {
        int i0 = s0 + off + g;
        uint_t u0 = (i0      < s1) ? pwp[i0]      : 0u;
        uint_t u1 = (i0 + 4  < s1) ? pwp[i0 + 4]  : 0u;
        uint_t u2 = (i0 + 8  < s1) ? pwp[i0 + 8]  : 0u;
        uint_t u3 = (i0 + 12 < s1) ? pwp[i0 + 12] : 0u;
        uint4 hv0 = *(const uint4*)(hbase + ((size_t)(u0 >> 16) << 9));
        uint4 hv1 = *(const uint4*)(hbase + ((size_t)(u1 >> 16) << 9));
        uint4 hv2 = *(const uint4*)(hbase + ((size_t)(u2 >> 16) << 9));
        uint4 hv3 = *(const uint4*)(hbase + ((size_t)(u3 >> 16) << 9));
        float pw0 = h2f(u0 & 0xffffu), pw1 = h2f(u1 & 0xffffu);
        float pw2 = h2f(u2 & 0xffffu), pw3 = h2f(u3 & 0xffffu);
        den += (pw0 + pw1) + (pw2 + pw3);
        fma8(a0, a1, a2, a3, hv0, pw0);
        fma8(a0, a1, a2, a3, hv1, pw1);
        fma8(a0, a1, a2, a3, hv2, pw2);
        fma8(a0, a1, a2, a3, hv3, pw3);
    }
    // reduce across the 4 edge-subgroups within each 32-lane half
#pragma unroll
    for (int off = 8; off <= 16; off <<= 1) {
        a0.x += __shfl_xor(a0.x, off); a0.y += __shfl_xor(a0.y, off);
        a1.x += __shfl_xor(a1.x, off); a1.y += __shfl_xor(a1.y, off);
        a2.x += __shfl_xor(a2.x, off); a2.y += __shfl_xor(a2.y, off);
        a3.x += __shfl_xor(a3.x, off); a3.y += __shfl_xor(a3.y, off);
        den  += __shfl_xor(den, off);
    }

    if (mode) {
        if (g == 0 && valid) {
            float inv = 1.f / den;
            float v[8] = {a0.x, a0.y, a1.x, a1.y, a2.x, a2.y, a3.x, a3.y};
            const float* bp = b1 + hh * HID + cg * 8;
#pragma unroll
            for (int j = 0; j < 8; ++j) {
                float t = v[j] * inv + bp[j];
                v[j] = (t > 0.f) ? t : __expf(t) - 1.f;
            }
            uint4 u;
            u.x = (uint_t)f2bf(v[0]) | ((uint_t)f2bf(v[1]) << 16);
            u.y = (uint_t)f2bf(v[2]) | ((uint_t)f2bf(v[3]) << 16);
            u.z = (uint_t)f2bf(v[4]) | ((uint_t)f2bf(v[5]) << 16);
            u.w = (uint_t)f2bf(v[6]) | ((uint_t)f2bf(v[7]) << 16);
            *(uint4*)(hout + (long)d * FDIM + hh * HID + cg * 8) = u;
        }
    } else {
        if (g == 0 && valid) {
            float inv = 1.f / den;
            float v[8] = {a0.x, a0.y, a1.x, a1.y, a2.x, a2.y, a3.x, a3.y};
            int zb = half * FDIM + hh * HID + cg * 8;
#pragma unroll
            for (int j = 0; j < 8; ++j) zsh[zb + j] = v[j] * inv;
        }
        __syncthreads();
        if (tid < 128) {                 // head-mean + b2 + ELU
            int node = tid >> 6, c = tid & 63;
            int dd = blockIdx.x * 2 + node;
            if (dd < N) {
                const float* zp = zsh + node * FDIM;
                float zv = 0.25f * (zp[c] + zp[64 + c] + zp[128 + c] + zp[192 + c])
                         + wsh[520 + c];
                zv = (zv > 0.f) ? zv : __expf(zv) - 1.f;
                zsh[node * FDIM + c] = zv;
            }
        }
        __syncthreads();
        if (tid < 16) {                  // GEMV [64x8] + bc
            int node = tid >> 3, o = tid & 7;
            int dd = blockIdx.x * 2 + node;
            if (dd < N) {
                float acc = wsh[512 + o];
                const float* zp = zsh + node * FDIM;
#pragma unroll 8
                for (int c = 0; c < 64; ++c) acc += zp[c] * wsh[c * 8 + o];
                fout[(long)dd * 8 + o] = acc;
            }
        }
    }
}

// ---------------- launch ----------------

extern "C" void kernel_launch(void* const* d_in, const int* in_sizes, int n_in,
                              void* d_out, int out_size, void* d_ws, size_t ws_size,
                              hipStream_t stream) {
    const float* x   = (const float*)d_in[0];
    const int*   ei  = (const int*)d_in[1];
    const float* W1  = (const float*)d_in[2];
    const float* as1 = (const float*)d_in[3];
    const float* ad1 = (const float*)d_in[4];
    const float* b1  = (const float*)d_in[5];
    const float* W2  = (const float*)d_in[6];
    const float* as2 = (const float*)d_in[7];
    const float* ad2 = (const float*)d_in[8];
    const float* b2  = (const float*)d_in[9];
    const float* Wc  = (const float*)d_in[10];
    const float* bc  = (const float*)d_in[11];
    float* out = (float*)d_out;

    const int N = NODES;
    const int E = in_sizes[1] / 2;
    const int Etot = E + N;

    char* ws = (char*)d_ws;
    size_t off = 0;
    auto alloc = [&](size_t bytes) {
        void* p = ws + off;
        off = (off + bytes + 255) & ~(size_t)255;
        return p;
    };
    ushort_t* hbf    = (ushort_t*)alloc((size_t)N * FDIM * 2);   // h (bf16), both layers
    ushort_t* hact   = (ushort_t*)alloc((size_t)N * FDIM * 2);   // act1 (bf16)
    float*    asrc   = (float*)alloc((size_t)N * HEADS * 4);
    float*    adst   = (float*)alloc((size_t)N * HEADS * 4);
    ushort_t* W2T    = (ushort_t*)alloc((size_t)FDIM * FDIM * 2);
    int*      deg    = (int*)alloc((size_t)N * 4);
    int*      rowst  = (int*)alloc((size_t)(N + 1) * 4);
    int*      cursor = (int*)alloc((size_t)N * 4);
    int*      bsum   = (int*)alloc(64 * 4);
    int2*     csr2   = (int2*)alloc((size_t)Etot * 8);
    uint_t*   pwb    = (uint_t*)alloc((size_t)Etot * HEADS * 4);

    const int tpb = 256;
    int egrid = (Etot + tpb - 1) / tpb;
    int nb = (N + 4095) / 4096;
    int NB = (N + 7) / 8;

    hipMemsetAsync(deg, 0, (size_t)N * 4, stream);

    // Merged: layer-1 gemm+alpha | W2T | histogram
    k_prep<<<NB + 256 + egrid, tpb, 0, stream>>>(x, W1, as1, ad1, W2, ei, E,
                                                 hbf, asrc, adst, W2T, deg, N, NB);
    k_scanA<<<nb, 256, 0, stream>>>(deg, bsum, N);
    k_scanB<<<1, 64, 0, stream>>>(bsum, rowst, nb, N);
    k_scanC<<<nb, 256, 0, stream>>>(deg, bsum, rowst, cursor, N);
    k_scatter<<<egrid, tpb, 0, stream>>>(ei, E, N, cursor, csr2);

    // Layer 1 aggregate (+b1, ELU)
    k_pw<<<egrid, tpb, 0, stream>>>(csr2, asrc, adst, pwb, Etot);
    k_agg<<<(N + 1) / 2, 256, 0, stream>>>(hbf, pwb, rowst, b1, nullptr, nullptr, nullptr,
                                           hact, nullptr, 1, Etot, N);

    // Layer 2 (gemm + fused alpha2)
    dim3 g2(FDIM / 64, (N + 63) / 64);
    k_gemm2<<<g2, 256, 0, stream>>>(hact, W2T, as2, ad2, hbf, asrc, adst, N);
    k_pw<<<egrid, tpb, 0, stream>>>(csr2, asrc, adst, pwb, Etot);
    k_agg<<<(N + 1) / 2, 256, 0, stream>>>(hbf, pwb, rowst, nullptr, b2, Wc, bc,
                                           nullptr, out, 0, Etot, N);
}